// Round 2
// 741.430 us; speedup vs baseline: 1.1812x; 1.1812x over previous
//
#include <hip/hip_runtime.h>
#include <math.h>

// Problem constants
#define S       2048
#define D       2048
#define EQ      2048   // N_Q_HEADS * HEAD_DIM
#define EK      512    // N_KV_HEADS * HEAD_DIM
#define ETOT    2560   // EQ + EK
#define NH      32
#define NKV     8
#define HD      64
#define KLEN    1024   // max(S*0.5, 2)

// Workspace layout (byte offsets)
#define OFF_COS   ((size_t)0)                    // [S][32] f32 = 256KB
#define OFF_SIN   ((size_t)(256u << 10))         // 256KB
#define OFF_QK    ((size_t)(1u << 20))           // [S][ETOT] f32 = 20MB
#define OFF_KT    ((size_t)(22u << 20))          // [NKV][64][S] f32 = 4MB
#define OFF_PART  ((size_t)(26u << 20))          // [1024][S] f32 = 8MB
#define OFF_VALS  ((size_t)(34u << 20))          // [S] f64 = 16KB
#define OFF_FLAGS ((size_t)((34u << 20) + (16u << 10)))   // [S] i32 = 8KB
#define OFF_ACCP  ((size_t)((34u << 20) + (32u << 10)))   // [32][S] f64 = 512KB

// ---------------------------------------------------------------------------
// 1) cos/sin tables in fp64 (fp32 arg reduction at pos~2047 gives ~1e-4 error,
//    j-correlated -> would destabilize the topk boundary).
__global__ void trig_kernel(float* __restrict__ cosT, float* __restrict__ sinT) {
  int idx = blockIdx.x * blockDim.x + threadIdx.x;  // S*32 = 65536
  int s = idx >> 5, i = idx & 31;
  double invf = 1.0 / pow(10000.0, (double)i / 32.0);
  double ang = (double)s * invf;
  cosT[idx] = (float)cos(ang);
  sinT[idx] = (float)sin(ang);
}

// ---------------------------------------------------------------------------
// 2) Fused gather + projection GEMM on the MATRIX CORES.
//    C[s][e] = sum_d embed[ids[s]][d] * W[e][d], fp32-accurate via fp16x2
//    split (Markidis): x*64 = x1 + x2 with x1=f16(x*64), x2=f16(x*64-x1);
//    a*b ~= (a1b1 + a1b2 + a2b1)/4096 computed by 3 x mfma_f32_16x16x32_f16
//    with fp32 accumulation. Per-product rel error ~2^-22 ~ fp32-chain class.
//    Tile 128x128, BK=32, 256 thr (2x2 waves, each 4x4 frags of 16x16).
//    LDS layout is fragment-ordered [chunk][lane][8] so every ds_read_b128 /
//    ds_write_b128 is stride-1 across lanes -> zero bank conflicts.
//    LDS = exactly 64KB (sA 32KB + sB 32KB); row-ids are loaded per-thread
//    straight from the 8KB L2-resident ids[] (no rowid LDS, no extra barrier).
//    Staging is reg-staged (global fp32 -> split -> ds_write), issue-early /
//    write-late (T14) so HBM/L2 latency hides under the MFMA block.
#define PBM 128
#define PBN 128
#define PBK 32
#define NKT (D / PBK)   // 64

typedef _Float16 f16x8 __attribute__((ext_vector_type(8)));
typedef float    f32x4 __attribute__((ext_vector_type(4)));

__global__ __launch_bounds__(256, 2) void proj_gemm_mfma(
    const int* __restrict__ ids, const float* __restrict__ embed,
    const float* __restrict__ Wq, const float* __restrict__ Wk,
    float* __restrict__ C) {
  // [buf][part(hi/lo)][8 chunks * 64 lanes * 8 f16] = 32KB each
  __shared__ _Float16 sA[2][2][PBM * PBK];
  __shared__ _Float16 sB[2][2][PBN * PBK];
  const int t = threadIdx.x;           // 0..255
  const int col0 = blockIdx.x * PBN;   // 20 col blocks
  const int row0 = blockIdx.y * PBM;   // 16 row blocks
  const float* Wbase = (col0 < EQ) ? (Wq + (size_t)col0 * D)
                                   : (Wk + (size_t)(col0 - EQ) * D);

  // Each thread owns 2 A-entries and 2 B-entries (entry = 8 consecutive k of
  // one row): e0 = t, e1 = t+256. Entry e -> chunk rt=e>>6, lane=e&63,
  // row = 16*rt + (lane&15), koff = (lane>>4)*8. LDS dest = e*8 halves
  // (lane-stride 16B -> conflict-free ds_write_b128).
  const float* srcA[2];
  const float* srcB[2];
  int ldsOff[2];
#pragma unroll
  for (int q = 0; q < 2; ++q) {
    const int e = t + q * 256;
    const int lane = e & 63, rt = e >> 6;
    const int r = rt * 16 + (lane & 15);
    const int koff = (lane >> 4) * 8;
    srcA[q] = embed + (size_t)ids[row0 + r] * D + koff;
    srcB[q] = Wbase + (size_t)r * D + koff;
    ldsOff[q] = e * 8;
  }

  const int ln = t & 63, w = t >> 6;
  const int wm = w >> 1, wn = w & 1;       // wave -> 64x64 quadrant
  const int aoff = ln * 8;                 // within-chunk f16 index

  f32x4 acc[4][4];
#pragma unroll
  for (int m = 0; m < 4; ++m)
#pragma unroll
    for (int n = 0; n < 4; ++n) {
      f32x4 z = {0.f, 0.f, 0.f, 0.f};
      acc[m][n] = z;
    }

  float4 va[2][2], vb[2][2];

  auto load_regs = [&](int k) {
#pragma unroll
    for (int q = 0; q < 2; ++q) {
      va[q][0] = *(const float4*)(srcA[q] + k);
      va[q][1] = *(const float4*)(srcA[q] + k + 4);
      vb[q][0] = *(const float4*)(srcB[q] + k);
      vb[q][1] = *(const float4*)(srcB[q] + k + 4);
    }
  };

  auto cvt_write = [&](int buf) {
#pragma unroll
    for (int q = 0; q < 2; ++q) {
      const float fa[8] = {va[q][0].x, va[q][0].y, va[q][0].z, va[q][0].w,
                           va[q][1].x, va[q][1].y, va[q][1].z, va[q][1].w};
      const float fb[8] = {vb[q][0].x, vb[q][0].y, vb[q][0].z, vb[q][0].w,
                           vb[q][1].x, vb[q][1].y, vb[q][1].z, vb[q][1].w};
      f16x8 ah1, ah2, bh1, bh2;
#pragma unroll
      for (int j = 0; j < 8; ++j) {
        float fs = fa[j] * 64.f;              // exact pow2 scale
        _Float16 h = (_Float16)fs;
        ah1[j] = h;
        ah2[j] = (_Float16)(fs - (float)h);   // exact residual, then rounded
        fs = fb[j] * 64.f;
        h = (_Float16)fs;
        bh1[j] = h;
        bh2[j] = (_Float16)(fs - (float)h);
      }
      *(f16x8*)&sA[buf][0][ldsOff[q]] = ah1;
      *(f16x8*)&sA[buf][1][ldsOff[q]] = ah2;
      *(f16x8*)&sB[buf][0][ldsOff[q]] = bh1;
      *(f16x8*)&sB[buf][1][ldsOff[q]] = bh2;
    }
  };

  // prologue: stage k-tile 0 into buf 0
  load_regs(0);
  cvt_write(0);
  __syncthreads();

  int cur = 0;
  for (int kt = 0; kt < NKT; ++kt) {
    const int nb = cur ^ 1;
    const bool more = (kt + 1 < NKT);
    if (more) load_regs((kt + 1) * PBK);     // issue early (T14)

    // compute from buf[cur]
    f16x8 a1[4], a2[4], b1[4], b2[4];
#pragma unroll
    for (int m = 0; m < 4; ++m) {
      const int c = (wm * 4 + m) * (16 * PBK) + aoff;
      a1[m] = *(const f16x8*)&sA[cur][0][c];
      a2[m] = *(const f16x8*)&sA[cur][1][c];
    }
#pragma unroll
    for (int n = 0; n < 4; ++n) {
      const int c = (wn * 4 + n) * (16 * PBK) + aoff;
      b1[n] = *(const f16x8*)&sB[cur][0][c];
      b2[n] = *(const f16x8*)&sB[cur][1][c];
    }
#pragma unroll
    for (int m = 0; m < 4; ++m)
#pragma unroll
      for (int n = 0; n < 4; ++n) {
        acc[m][n] = __builtin_amdgcn_mfma_f32_16x16x32_f16(a1[m], b1[n], acc[m][n], 0, 0, 0);
        acc[m][n] = __builtin_amdgcn_mfma_f32_16x16x32_f16(a1[m], b2[n], acc[m][n], 0, 0, 0);
        acc[m][n] = __builtin_amdgcn_mfma_f32_16x16x32_f16(a2[m], b1[n], acc[m][n], 0, 0, 0);
      }

    if (more) cvt_write(nb);                 // write late, after MFMA block
    __syncthreads();
    cur = nb;
  }

  // C/D layout (HW-verified, dtype-independent): col = lane&15,
  // row = (lane>>4)*4 + reg. Undo the 64*64 scale.
  const float inv = 1.f / 4096.f;
  const int colb = col0 + wn * 64 + (ln & 15);
  const int rowb = row0 + wm * 64 + (ln >> 4) * 4;
#pragma unroll
  for (int m = 0; m < 4; ++m)
#pragma unroll
    for (int j = 0; j < 4; ++j) {
      float* dst = C + (size_t)(rowb + m * 16 + j) * ETOT + colb;
#pragma unroll
      for (int n = 0; n < 4; ++n) dst[n * 16] = acc[m][n][j] * inv;
    }
}

// ---------------------------------------------------------------------------
// 3) RoPE on q, in place. One thread owns the (i, i+32) pair -> no race.
__global__ void rope_q_kernel(float* __restrict__ qk,
                              const float* __restrict__ cosT,
                              const float* __restrict__ sinT) {
  int idx = blockIdx.x * blockDim.x + threadIdx.x;  // S * NH * 32
  int s = idx >> 10;
  int rem = idx & 1023;
  int h = rem >> 5, i = rem & 31;
  float c = cosT[(s << 5) + i], sn = sinT[(s << 5) + i];
  float* p = qk + (size_t)s * ETOT + h * HD + i;
  float x1 = p[0], x2 = p[32];
  p[0]  = fmaf(x1, c, -x2 * sn);
  p[32] = fmaf(x2, c,  x1 * sn);
}

// 4) RoPE on k -> transposed kT[kv][d][s], via LDS tile so both the qk reads
//    and the kT writes are coalesced 256B rows.
__global__ __launch_bounds__(256) void rope_k_kernel(
    const float* __restrict__ qk, float* __restrict__ kT,
    const float* __restrict__ cosT, const float* __restrict__ sinT) {
  __shared__ float tile[64][65];
  __shared__ float ct[64][33];
  __shared__ float st[64][33];
  const int kv = blockIdx.x;       // 0..7
  const int s0 = blockIdx.y * 64;  // 0..2047
  const int t = threadIdx.x;
  {
    const int c = t & 63, r = t >> 6;
#pragma unroll
    for (int p = 0; p < 16; ++p)
      tile[r + 4 * p][c] = qk[(size_t)(s0 + r + 4 * p) * ETOT + EQ + kv * HD + c];
  }
  {
    const int i = t & 31, r = t >> 5;
#pragma unroll
    for (int p = 0; p < 8; ++p) {
      ct[r + 8 * p][i] = cosT[(s0 + r + 8 * p) * 32 + i];
      st[r + 8 * p][i] = sinT[(s0 + r + 8 * p) * 32 + i];
    }
  }
  __syncthreads();
  const int s = t & 63, dbase = t >> 6;
#pragma unroll
  for (int p = 0; p < 16; ++p) {
    const int d = dbase + 4 * p;
    float v;
    if (d < 32) {
      const float c = ct[s][d], sn = st[s][d];
      const float x1 = tile[s][d], x2 = tile[s][d + 32];
      v = fmaf(x1, c, -x2 * sn);
    } else {
      const float c = ct[s][d - 32], sn = st[s][d - 32];
      const float x1 = tile[s][d - 32], x2 = tile[s][d];
      v = fmaf(x2, c, x1 * sn);
    }
    kT[(size_t)(kv * HD + d) * S + s0 + s] = v;
  }
}

// ---------------------------------------------------------------------------
// 5) Attention. R4 structure, one-deep prefetch on the d2-loop.
__global__ __launch_bounds__(256) void attn_kernel(
    const float* __restrict__ qk, const float* __restrict__ kT,
    float* __restrict__ part) {
  const int h = blockIdx.x;    // 0..31
  const int sb = blockIdx.y;   // 0..31
  const int t = threadIdx.x;
  const float* kTh = kT + (size_t)(h >> 2) * HD * S;
  __shared__ float qlds[16][64];
  __shared__ float wred[4][16];
  float colacc[8];
#pragma unroll
  for (int u = 0; u < 8; ++u) colacc[u] = 0.f;
  const int c0 = t * 8;

  for (int ch = 0; ch < 4; ++ch) {
    const int row0 = sb * 64 + ch * 16;
    __syncthreads();
    {
      const int r = t >> 6, dd = t & 63;
#pragma unroll
      for (int rr = 0; rr < 4; ++rr)
        qlds[r + rr * 4][dd] = qk[(size_t)(row0 + r + rr * 4) * ETOT + h * HD + dd];
    }
    __syncthreads();
    float acc[16][8];
#pragma unroll
    for (int r = 0; r < 16; ++r)
#pragma unroll
      for (int u = 0; u < 8; ++u) acc[r][u] = 0.f;

    float4 c0a = *(const float4*)(kTh + c0);
    float4 c0b = *(const float4*)(kTh + c0 + 4);
    float4 c1a = *(const float4*)(kTh + (size_t)S + c0);
    float4 c1b = *(const float4*)(kTh + (size_t)S + c0 + 4);
    for (int d2 = 0; d2 < HD; d2 += 2) {
      const int dn = (d2 + 2) & (HD - 1);   // wrap; last prefetch discarded
      const float4 n0a = *(const float4*)(kTh + (size_t)dn * S + c0);
      const float4 n0b = *(const float4*)(kTh + (size_t)dn * S + c0 + 4);
      const float4 n1a = *(const float4*)(kTh + (size_t)(dn + 1) * S + c0);
      const float4 n1b = *(const float4*)(kTh + (size_t)(dn + 1) * S + c0 + 4);
      float2 q2[16];
#pragma unroll
      for (int r = 0; r < 16; ++r) q2[r] = *(const float2*)&qlds[r][d2];
      {
        const float kv[8] = {c0a.x, c0a.y, c0a.z, c0a.w, c0b.x, c0b.y, c0b.z, c0b.w};
#pragma unroll
        for (int r = 0; r < 16; ++r) {
          const float qd = q2[r].x;
#pragma unroll
          for (int u = 0; u < 8; ++u) acc[r][u] = fmaf(qd, kv[u], acc[r][u]);
        }
      }
      {
        const float kv[8] = {c1a.x, c1a.y, c1a.z, c1a.w, c1b.x, c1b.y, c1b.z, c1b.w};
#pragma unroll
        for (int r = 0; r < 16; ++r) {
          const float qd = q2[r].y;
#pragma unroll
          for (int u = 0; u < 8; ++u) acc[r][u] = fmaf(qd, kv[u], acc[r][u]);
        }
      }
      c0a = n0a; c0b = n0b; c1a = n1a; c1b = n1b;
    }
    float p[16];
#pragma unroll
    for (int r = 0; r < 16; ++r) {
      p[r] = 0.f;
#pragma unroll
      for (int u = 0; u < 8; ++u) {
        acc[r][u] = expf(acc[r][u]);
        p[r] += acc[r][u];
      }
    }
#pragma unroll
    for (int off = 32; off > 0; off >>= 1)
#pragma unroll
      for (int r = 0; r < 16; ++r) p[r] += __shfl_xor(p[r], off, 64);
    if ((t & 63) == 0) {
#pragma unroll
      for (int r = 0; r < 16; ++r) wred[t >> 6][r] = p[r];
    }
    __syncthreads();
#pragma unroll
    for (int r = 0; r < 16; ++r) {
      const float Z = wred[0][r] + wred[1][r] + wred[2][r] + wred[3][r];
      const float inv = 1.f / Z;
#pragma unroll
      for (int u = 0; u < 8; ++u) colacc[u] = fmaf(acc[r][u], inv, colacc[u]);
    }
  }
  const int b = h * 32 + sb;
  *(float4*)(part + (size_t)b * S + c0)     = make_float4(colacc[0], colacc[1], colacc[2], colacc[3]);
  *(float4*)(part + (size_t)b * S + c0 + 4) = make_float4(colacc[4], colacc[5], colacc[6], colacc[7]);
}

// ---------------------------------------------------------------------------
// 6) fp64 column totals, two stages (same left-to-right order as R3/R4).
__global__ void vals1_kernel(const float* __restrict__ part,
                             double* __restrict__ accp) {
  int j = blockIdx.x * 256 + threadIdx.x;  // 0..2047
  int g = blockIdx.y;                      // 0..31
  const float* p = part + (size_t)g * 32 * S + j;
  double s = 0.0;
  for (int b = 0; b < 32; ++b) s += (double)p[(size_t)b * S];
  accp[(size_t)g * S + j] = s;
}
__global__ void vals2_kernel(const double* __restrict__ accp,
                             double* __restrict__ vals) {
  int j = blockIdx.x * 256 + threadIdx.x;
  double s = 0.0;
  for (int g = 0; g < 32; ++g) s += accp[(size_t)g * S + j];
  vals[j] = s;
}

// 7) Exact rank, one block per j. Same predicate (tie-break: lower index
//    wins, matching lax.top_k); deterministic.
__global__ __launch_bounds__(256) void flags_kernel(
    const double* __restrict__ vals, int* __restrict__ flags) {
  const int j = blockIdx.x;       // 0..2047
  const int t = threadIdx.x;
  const double v = vals[j];
  int rank = 0;
  for (int j2 = t; j2 < S; j2 += 256) {
    const double v2 = vals[j2];
    rank += (v2 > v) || (v2 == v && j2 < j);
  }
#pragma unroll
  for (int off = 32; off > 0; off >>= 1) rank += __shfl_xor(rank, off, 64);
  __shared__ int red[4];
  if ((t & 63) == 0) red[t >> 6] = rank;
  __syncthreads();
  if (t == 0)
    flags[j] = ((red[0] + red[1] + red[2] + red[3]) < KLEN) ? 1 : 0;
}

// 8) Compact selected indices (ascending) + write tokens/indices + append S-1.
__global__ __launch_bounds__(1024) void emit_kernel(
    const int* __restrict__ flags, const int* __restrict__ ids,
    int* __restrict__ out) {
  __shared__ int fl[S];
  __shared__ int csum[32];
  __shared__ int cpre[32];
  const int t = threadIdx.x;
  for (int j = t; j < S; j += 1024) fl[j] = flags[j];
  __syncthreads();
  if (t < 32) {
    int s = 0;
    for (int i = 0; i < 64; ++i) s += fl[t * 64 + i];
    csum[t] = s;
  }
  __syncthreads();
  if (t == 0) {
    int run = 0;
    for (int c = 0; c < 32; ++c) { cpre[c] = run; run += csum[c]; }
  }
  __syncthreads();
  for (int j = t; j < S; j += 1024) {
    if (fl[j]) {
      int pos = cpre[j >> 6];
      for (int j2 = j & ~63; j2 < j; ++j2) pos += fl[j2];
      out[pos] = ids[j];            // pruned tokens [0..1023]
      out[KLEN + 1 + pos] = j;      // indices [1025..2048]
    }
  }
  if (t == 0) {
    out[KLEN] = ids[S - 1];
    out[KLEN + 1 + KLEN] = S - 1;
  }
}

// ---------------------------------------------------------------------------
extern "C" void kernel_launch(void* const* d_in, const int* in_sizes, int n_in,
                              void* d_out, int out_size, void* d_ws, size_t ws_size,
                              hipStream_t stream) {
  const int* ids = (const int*)d_in[0];
  const float* embed = (const float*)d_in[1];
  const float* Wq = (const float*)d_in[2];
  const float* Wk = (const float*)d_in[3];
  int* out = (int*)d_out;
  char* ws = (char*)d_ws;
  float* cosT = (float*)(ws + OFF_COS);
  float* sinT = (float*)(ws + OFF_SIN);
  float* qk   = (float*)(ws + OFF_QK);
  float* kT   = (float*)(ws + OFF_KT);
  float* part = (float*)(ws + OFF_PART);
  double* vals = (double*)(ws + OFF_VALS);
  int* flags  = (int*)(ws + OFF_FLAGS);
  double* accp = (double*)(ws + OFF_ACCP);

  trig_kernel<<<256, 256, 0, stream>>>(cosT, sinT);
  proj_gemm_mfma<<<dim3(ETOT / PBN, S / PBM), 256, 0, stream>>>(ids, embed, Wq, Wk, qk);
  rope_q_kernel<<<(S * NH * 32) / 256, 256, 0, stream>>>(qk, cosT, sinT);
  rope_k_kernel<<<dim3(NKV, S / 64), 256, 0, stream>>>(qk, kT, cosT, sinT);
  attn_kernel<<<dim3(NH, 32), 256, 0, stream>>>(qk, kT, part);
  vals1_kernel<<<dim3(S / 256, 32), 256, 0, stream>>>(part, accp);
  vals2_kernel<<<S / 256, 256, 0, stream>>>(accp, vals);
  flags_kernel<<<S, 256, 0, stream>>>(vals, flags);
  emit_kernel<<<1, 1024, 0, stream>>>(flags, ids, out);
}